// Round 3
// baseline (969.851 us; speedup 1.0000x reference)
//
#include <hip/hip_runtime.h>

// GTrXL fused pipeline v3: 8-phase 256^2 GEMM (T2+T3+T4+T5) for big GEMMs,
// mask-aware attention bounds, fused GRU epilogues, XCD-aware swizzles.

typedef __bf16 bf16_t;
typedef __bf16 bf16x4 __attribute__((ext_vector_type(4)));
typedef __bf16 bf16x8 __attribute__((ext_vector_type(8)));
typedef float f32x4 __attribute__((ext_vector_type(4)));

typedef __attribute__((address_space(1))) const void* GPtr;
typedef __attribute__((address_space(3))) void* LPtr;

// ---------------- fp32 -> bf16 convert ----------------
__global__ __launch_bounds__(256) void cvt_kernel(const float* __restrict__ in,
                                                  bf16_t* __restrict__ out, int n4) {
  int i = blockIdx.x * 256 + threadIdx.x;
  if (i >= n4) return;
  f32x4 v = ((const f32x4*)in)[i];
  bf16x4 o;
  o[0] = (bf16_t)v[0]; o[1] = (bf16_t)v[1]; o[2] = (bf16_t)v[2]; o[3] = (bf16_t)v[3];
  ((bf16x4*)out)[i] = o;
}

// ---------------- batched weight transpose: W[K][N] f32 -> WT[N][K] bf16 ----------------
struct WtArgs {
  const float* src[18];
  bf16_t* dst[18];
  int kdim[18];
  int ndim[18];
  int tile_end[18];
};

__global__ __launch_bounds__(256) void wt_batch(WtArgs a) {
  int t = blockIdx.x;
  int i = 0;
  while (i < 17 && t >= a.tile_end[i]) ++i;
  int lt = t - (i ? a.tile_end[i - 1] : 0);
  const float* W = a.src[i];
  bf16_t* WT = a.dst[i];
  int K = a.kdim[i], N = a.ndim[i];
  int ntx = N >> 6;
  int n0 = (lt % ntx) * 64, k0 = (lt / ntx) * 64;
  __shared__ float tbuf[64][65];
  int tid = threadIdx.x;
  int c = tid & 63, r0 = tid >> 6;
  #pragma unroll
  for (int p = 0; p < 16; ++p) {
    int r = r0 + p * 4;
    tbuf[r][c] = W[(size_t)(k0 + r) * N + n0 + c];
  }
  __syncthreads();
  #pragma unroll
  for (int p = 0; p < 16; ++p) {
    int r = r0 + p * 4;
    WT[(size_t)(n0 + r) * K + k0 + c] = (bf16_t)tbuf[c][r];
  }
}

// ---------------- LayerNorm over D=1024, optional row-concat of two sources ----------------
__global__ __launch_bounds__(256) void ln_kernel(const float* __restrict__ srcA,
                                                 const float* __restrict__ srcB, int splitRow,
                                                 const float* __restrict__ g,
                                                 const float* __restrict__ be,
                                                 bf16_t* __restrict__ out) {
  const int row = blockIdx.x, tid = threadIdx.x;
  const float* src = (srcB != nullptr && row >= splitRow)
                         ? srcB + (size_t)(row - splitRow) * 1024
                         : srcA + (size_t)row * 1024;
  f32x4 x = ((const f32x4*)src)[tid];
  __shared__ float red[8];
  float s = x[0] + x[1] + x[2] + x[3];
  #pragma unroll
  for (int o = 32; o; o >>= 1) s += __shfl_down(s, o);
  if ((tid & 63) == 0) red[tid >> 6] = s;
  __syncthreads();
  if (tid == 0) red[4] = (red[0] + red[1] + red[2] + red[3]) * (1.f / 1024.f);
  __syncthreads();
  const float mean = red[4];
  f32x4 d = x - mean;
  float s2 = d[0] * d[0] + d[1] * d[1] + d[2] * d[2] + d[3] * d[3];
  #pragma unroll
  for (int o = 32; o; o >>= 1) s2 += __shfl_down(s2, o);
  if ((tid & 63) == 0) red[tid >> 6] = s2;
  __syncthreads();
  if (tid == 0) red[5] = rsqrtf((red[0] + red[1] + red[2] + red[3]) * (1.f / 1024.f) + 1e-5f);
  __syncthreads();
  const float rstd = red[5];
  f32x4 gg = ((const f32x4*)g)[tid], bb = ((const f32x4*)be)[tid];
  bf16x4 o4;
  #pragma unroll
  for (int j = 0; j < 4; ++j) o4[j] = (bf16_t)(d[j] * rstd * gg[j] + bb[j]);
  ((bf16x4*)(out + (size_t)row * 1024))[tid] = o4;
}

// ---------------- 128^2 MFMA GEMM (small shapes) with fused epilogues ----------------
// act: 0 none, 1 relu, 4 gate_rz, 5 gate_combine
__global__ __launch_bounds__(256) void gemm_bf16(const bf16_t* __restrict__ A,
                                                 const bf16_t* __restrict__ BT,
                                                 const float* __restrict__ bias,
                                                 float* __restrict__ Cf, bf16_t* __restrict__ Cb,
                                                 const float* __restrict__ Cacc, int ldacc,
                                                 const float* __restrict__ xin,
                                                 const float* __restrict__ zin,
                                                 int M, int N, int K, int act) {
  __shared__ bf16_t As[128 * 32];
  __shared__ bf16_t Bs[128 * 32];
  const int tid = threadIdx.x, lane = tid & 63, wid = tid >> 6;
  const int nx = gridDim.x;
  int flat = blockIdx.y * nx + blockIdx.x;
  int nwg = nx * gridDim.y;
  int q8 = nwg >> 3, r8 = nwg & 7;
  int xcd = flat & 7, idx = flat >> 3;
  int wg = (xcd < r8) ? xcd * (q8 + 1) + idx : r8 * (q8 + 1) + (xcd - r8) * q8 + idx;
  const int m0 = (wg / nx) * 128, n0 = (wg % nx) * 128;
  const int wm = (wid >> 1) * 64, wn = (wid & 1) * 64;
  const int mrow = lane & 15, kq = lane >> 4;
  f32x4 acc[4][4] = {};
  for (int k0 = 0; k0 < K; k0 += 32) {
    #pragma unroll
    for (int p = 0; p < 2; ++p) {
      int cbase = p * 256 + wid * 64;
      int c = cbase + lane;
      const bf16_t* ga = A + (size_t)(m0 + (c >> 2)) * K + k0 + (c & 3) * 8;
      const bf16_t* gb = BT + (size_t)(n0 + (c >> 2)) * K + k0 + (c & 3) * 8;
      __builtin_amdgcn_global_load_lds((GPtr)ga, (LPtr)(&As[cbase * 8]), 16, 0, 0);
      __builtin_amdgcn_global_load_lds((GPtr)gb, (LPtr)(&Bs[cbase * 8]), 16, 0, 0);
    }
    __syncthreads();
    bf16x8 af[4], bfr[4];
    #pragma unroll
    for (int i = 0; i < 4; ++i) {
      af[i] = *(const bf16x8*)&As[(wm + i * 16 + mrow) * 32 + kq * 8];
      bfr[i] = *(const bf16x8*)&Bs[(wn + i * 16 + mrow) * 32 + kq * 8];
    }
    #pragma unroll
    for (int i = 0; i < 4; ++i)
      #pragma unroll
      for (int j = 0; j < 4; ++j)
        acc[i][j] = __builtin_amdgcn_mfma_f32_16x16x32_bf16(af[i], bfr[j], acc[i][j], 0, 0, 0);
    __syncthreads();
  }
  #pragma unroll
  for (int i = 0; i < 4; ++i) {
    #pragma unroll
    for (int j = 0; j < 4; ++j) {
      int colb = n0 + wn + j * 16 + mrow;
      #pragma unroll
      for (int r2 = 0; r2 < 4; ++r2) {
        int row = m0 + wm + i * 16 + kq * 4 + r2;
        float vv = acc[i][j][r2];
        if (act <= 1) {
          if (bias) vv += bias[colb];
          if (act == 1) vv = fmaxf(vv, 0.f);
          size_t idxN = (size_t)row * N + colb;
          if (Cf) Cf[idxN] = vv;
          if (Cb) Cb[idxN] = (bf16_t)vv;
        } else if (act == 4) {
          vv += Cacc[(size_t)row * ldacc + colb];
          if (colb < 1024) {
            float r = 1.f / (1.f + __expf(-vv));
            Cb[(size_t)row * 1024 + colb] = (bf16_t)(r * xin[(size_t)row * 1024 + colb]);
          } else {
            float z = 1.f / (1.f + __expf(-(vv - bias[colb - 1024])));
            Cf[(size_t)row * 1024 + colb - 1024] = z;
          }
        } else {
          vv += Cacc[(size_t)row * ldacc + colb];
          float hh = tanhf(vv);
          size_t e = (size_t)row * 1024 + colb;
          float xx = xin[e], zz = zin[e];
          float o = xx + zz * (hh - xx);
          Cf[e] = o;
          if (Cb) Cb[e] = (bf16_t)o;
        }
      }
    }
  }
}

// ---------------- 8-phase 256^2 GEMM (T2 swizzle + T3/T4 counted vmcnt + T5 setprio) ----------
// M,N %256==0, K%128==0. A[M][K], BT[N][K] bf16. act: 0 none, 1 relu, 4 gate_rz.
#define MFMA_QUAD(MH, NH)                                                                     \
  _Pragma("unroll") for (int ii = 0; ii < 4; ++ii)                                            \
  _Pragma("unroll") for (int jj = 0; jj < 2; ++jj)                                            \
  _Pragma("unroll") for (int ks = 0; ks < 2; ++ks)                                            \
    acc[(MH)*4 + ii][(NH)*2 + jj] = __builtin_amdgcn_mfma_f32_16x16x32_bf16(                  \
        a[ii][ks], bfr[(NH)*2 + jj][ks], acc[(MH)*4 + ii][(NH)*2 + jj], 0, 0, 0);

#define PH_SYNC()                                                                             \
  __builtin_amdgcn_s_barrier();                                                               \
  asm volatile("s_waitcnt lgkmcnt(0)" ::: "memory");                                          \
  __builtin_amdgcn_sched_barrier(0);                                                          \
  __builtin_amdgcn_s_setprio(1)

#define PH_END()                                                                              \
  __builtin_amdgcn_s_setprio(0);                                                              \
  __builtin_amdgcn_s_barrier();                                                               \
  __builtin_amdgcn_sched_barrier(0)

#define PH_END_VM()                                                                           \
  __builtin_amdgcn_s_setprio(0);                                                              \
  asm volatile("s_waitcnt vmcnt(4)" ::: "memory");                                            \
  __builtin_amdgcn_s_barrier();                                                               \
  __builtin_amdgcn_sched_barrier(0)

__global__ __launch_bounds__(512, 2) void gemm256(const bf16_t* __restrict__ A,
                                                  const bf16_t* __restrict__ BT,
                                                  const float* __restrict__ bias,
                                                  float* __restrict__ Cf,
                                                  bf16_t* __restrict__ Cb,
                                                  const float* __restrict__ Cacc, int ldacc,
                                                  const float* __restrict__ xin,
                                                  int M, int N, int K, int act) {
  __shared__ bf16_t lds[65536];  // 2 bufs x (A 256x64 + B 256x64) = 128KB
  const int tid = threadIdx.x, lane = tid & 63, w = tid >> 6;
  const int mrow = lane & 15, kq = lane >> 4;
  const int nx = N >> 8;
  {
  }
  int nwg = gridDim.x;
  int flat = blockIdx.x;
  int q8 = nwg >> 3, r8 = nwg & 7;
  int xcd = flat & 7, idxb = flat >> 3;
  int wg = (xcd < r8) ? xcd * (q8 + 1) + idxb : r8 * (q8 + 1) + (xcd - r8) * q8 + idxb;
  const int m0 = (wg / nx) * 256, n0 = (wg % nx) * 256;

  const bf16_t* pA = A + (size_t)m0 * K;
  const bf16_t* pB = BT + (size_t)n0 * K;

  // stage one 16KB half-tile (2 global_load_lds per thread); source col pre-swizzled
  auto stage = [&](const bf16_t* base, int kt, int hh, int buf, int area) {
    #pragma unroll
    for (int li = 0; li < 2; ++li) {
      int row = li * 64 + w * 8 + (lane >> 3);
      const bf16_t* src =
          base + (size_t)(hh * 128 + row) * K + kt * 64 + (((lane & 7) ^ (lane >> 3)) << 3);
      __builtin_amdgcn_global_load_lds(
          (GPtr)src, (LPtr)&lds[buf * 32768 + area * 16384 + hh * 8192 + li * 4096 + w * 512],
          16, 0, 0);
    }
  };
  auto ldA = [&](int buf, int i, int ks) -> bf16x8 {
    int row = i * 16 + mrow;
    int off = (row << 6) + ((ks * 32 + kq * 8) ^ ((row & 7) << 3));
    return *(const bf16x8*)&lds[buf * 32768 + (w >> 2) * 8192 + off];
  };
  auto ldB = [&](int buf, int j, int ks) -> bf16x8 {
    int row = (w & 1) * 64 + j * 16 + mrow;
    int off = (row << 6) + ((ks * 32 + kq * 8) ^ ((row & 7) << 3));
    return *(const bf16x8*)&lds[buf * 32768 + 16384 + ((w & 3) >> 1) * 8192 + off];
  };

  f32x4 acc[8][4] = {};
  bf16x8 a[4][2], bfr[4][2];

  const int KT = K >> 6;
  // prologue: kt0 full -> buf0; kt1 B -> buf1
  stage(pA, 0, 0, 0, 0);
  stage(pA, 0, 1, 0, 0);
  stage(pB, 0, 0, 0, 1);
  stage(pB, 0, 1, 0, 1);
  stage(pB, 1, 0, 1, 1);
  stage(pB, 1, 1, 1, 1);
  asm volatile("s_waitcnt vmcnt(4)" ::: "memory");
  __builtin_amdgcn_s_barrier();
  __builtin_amdgcn_sched_barrier(0);

  for (int it = 0; it < KT / 2; ++it) {
    int kt = 2 * it;
    int ktA1 = min(kt + 1, KT - 1);
    int kt2 = min(kt + 2, KT - 1);
    int kt3 = min(kt + 3, KT - 1);
    // ph1: quad(m0,n0) of kt (buf0)
    #pragma unroll
    for (int ii = 0; ii < 4; ++ii) { a[ii][0] = ldA(0, ii, 0); a[ii][1] = ldA(0, ii, 1); }
    #pragma unroll
    for (int jj = 0; jj < 2; ++jj) { bfr[jj][0] = ldB(0, jj, 0); bfr[jj][1] = ldB(0, jj, 1); }
    stage(pA, ktA1, 0, 1, 0);
    PH_SYNC(); MFMA_QUAD(0, 0); PH_END();
    // ph2: quad(m0,n1)
    #pragma unroll
    for (int jj = 0; jj < 2; ++jj) { bfr[2 + jj][0] = ldB(0, 2 + jj, 0); bfr[2 + jj][1] = ldB(0, 2 + jj, 1); }
    stage(pA, ktA1, 1, 1, 0);
    PH_SYNC(); MFMA_QUAD(0, 1); PH_END();
    // ph3: quad(m1,n0)
    #pragma unroll
    for (int ii = 0; ii < 4; ++ii) { a[ii][0] = ldA(0, 4 + ii, 0); a[ii][1] = ldA(0, 4 + ii, 1); }
    stage(pB, kt2, 0, 0, 1);
    PH_SYNC(); MFMA_QUAD(1, 0); PH_END();
    // ph4: quad(m1,n1); counted vmcnt before barrier
    stage(pB, kt2, 1, 0, 1);
    PH_SYNC(); MFMA_QUAD(1, 1); PH_END_VM();
    // ph5: quad(m0,n0) of kt+1 (buf1)
    #pragma unroll
    for (int ii = 0; ii < 4; ++ii) { a[ii][0] = ldA(1, ii, 0); a[ii][1] = ldA(1, ii, 1); }
    #pragma unroll
    for (int jj = 0; jj < 2; ++jj) { bfr[jj][0] = ldB(1, jj, 0); bfr[jj][1] = ldB(1, jj, 1); }
    stage(pA, kt2, 0, 0, 0);
    PH_SYNC(); MFMA_QUAD(0, 0); PH_END();
    // ph6
    #pragma unroll
    for (int jj = 0; jj < 2; ++jj) { bfr[2 + jj][0] = ldB(1, 2 + jj, 0); bfr[2 + jj][1] = ldB(1, 2 + jj, 1); }
    stage(pA, kt2, 1, 0, 0);
    PH_SYNC(); MFMA_QUAD(0, 1); PH_END();
    // ph7
    #pragma unroll
    for (int ii = 0; ii < 4; ++ii) { a[ii][0] = ldA(1, 4 + ii, 0); a[ii][1] = ldA(1, 4 + ii, 1); }
    stage(pB, kt3, 0, 1, 1);
    PH_SYNC(); MFMA_QUAD(1, 0); PH_END();
    // ph8
    stage(pB, kt3, 1, 1, 1);
    PH_SYNC(); MFMA_QUAD(1, 1); PH_END_VM();
  }

  // epilogue
  #pragma unroll
  for (int i = 0; i < 8; ++i) {
    #pragma unroll
    for (int j = 0; j < 4; ++j) {
      int colb = n0 + (w & 3) * 64 + j * 16 + mrow;
      #pragma unroll
      for (int r2 = 0; r2 < 4; ++r2) {
        int row = m0 + (w >> 2) * 128 + i * 16 + kq * 4 + r2;
        float vv = acc[i][j][r2];
        if (act <= 1) {
          if (bias) vv += bias[colb];
          if (act == 1) vv = fmaxf(vv, 0.f);
          size_t idxN = (size_t)row * N + colb;
          if (Cf) Cf[idxN] = vv;
          if (Cb) Cb[idxN] = (bf16_t)vv;
        } else {  // act 4
          vv += Cacc[(size_t)row * ldacc + colb];
          if (colb < 1024) {
            float r = 1.f / (1.f + __expf(-vv));
            Cb[(size_t)row * 1024 + colb] = (bf16_t)(r * xin[(size_t)row * 1024 + colb]);
          } else {
            float z = 1.f / (1.f + __expf(-(vv - bias[colb - 1024])));
            Cf[(size_t)row * 1024 + colb - 1024] = z;
          }
        }
      }
    }
  }
}

// ---------------- value transpose: kv val-half -> vT[(b*16+h)*64+d][f] ----------------
__global__ __launch_bounds__(256) void vT_kernel(const bf16_t* __restrict__ kv,
                                                 bf16_t* __restrict__ vT) {
  int ft = blockIdx.x;
  int bh = blockIdx.y;
  int b = bh >> 4, h = bh & 15;
  __shared__ bf16_t t[64][68];
  int tid = threadIdx.x;
  {
    int dq = (tid & 15) * 4, fr = tid >> 4;
    #pragma unroll
    for (int p = 0; p < 4; ++p) {
      int fi = fr + p * 16;
      const bf16_t* src = kv + ((size_t)((ft * 64 + fi) * 8 + b)) * 2048 + 1024 + h * 64 + dq;
      *(bf16x4*)&t[fi][dq] = *(const bf16x4*)src;
    }
  }
  __syncthreads();
  {
    int fl = tid & 63, dr = tid >> 6;
    #pragma unroll
    for (int p = 0; p < 16; ++p) {
      int d = dr + p * 4;
      vT[((size_t)(bh * 64 + d)) * 1024 + ft * 64 + fl] = t[fl][d];
    }
  }
}

// ---------------- fused rel-pos attention (mask-aware bounds) ----------------
#define SC_RS 1032
__global__ __launch_bounds__(512) void attn_kernel(const bf16_t* __restrict__ q,
                                                   const bf16_t* __restrict__ kv,
                                                   const bf16_t* __restrict__ rpos,
                                                   const bf16_t* __restrict__ vT,
                                                   const float* __restrict__ u,
                                                   const float* __restrict__ v,
                                                   bf16_t* __restrict__ av) {
  const int bh = blockIdx.x, st = blockIdx.y;
  const int b = bh >> 4, h = bh & 15;
  const int s0 = st * 32;
  const int tid = threadIdx.x, lane = tid & 63, w = tid >> 6;
  const int mrow = lane & 15, kq = lane >> 4;
  const int sb = w & 1, fg = w >> 1;

  const int nc1 = (s0 + 671) >> 7;                        // content chunks (f <= s0+543)
  const int c0 = (s0 >= 480) ? 0 : ((480 - s0) >> 7);     // first rpos chunk
  const int nkk = (s0 + 575) >> 5;                        // AV k-slices

  __shared__ bf16_t sc[32 * SC_RS];
  __shared__ bf16_t chunk[2][128 * 64];
  __shared__ bf16_t qu[32][72], qv[32][72];
  __shared__ float rrecip[32];

  {
    int sl = tid >> 4, dq = (tid & 15) * 4;
    const bf16_t* qp = q + ((size_t)((s0 + sl) * 8 + b)) * 1024 + h * 64 + dq;
    bf16x4 q4 = *(const bf16x4*)qp;
    f32x4 uu = *(const f32x4*)(u + h * 64 + dq);
    f32x4 vv = *(const f32x4*)(v + h * 64 + dq);
    #pragma unroll
    for (int j = 0; j < 4; ++j) {
      float qf = (float)q4[j];
      qu[sl][dq + j] = (bf16_t)((qf + uu[j]) * 0.125f);
      qv[sl][dq + j] = (bf16_t)((qf + vv[j]) * 0.125f);
    }
  }

  auto stage = [&](const bf16_t* base, size_t rstride, int f0, int bufi) {
    #pragma unroll
    for (int li = 0; li < 2; ++li) {
      int r = w * 16 + li * 8 + (lane >> 3);
      int cbx = ((lane & 7) * 16) ^ ((r & 7) << 4);
      const bf16_t* src = base + (size_t)(f0 + r) * rstride + (cbx >> 1);
      __builtin_amdgcn_global_load_lds((GPtr)src, (LPtr)(&chunk[bufi][w * 1024 + li * 512]), 16,
                                       0, 0);
    }
  };
  const bf16_t* kbase = kv + (size_t)b * 2048 + h * 64;
  const bf16_t* rbase = rpos + h * 64;

  stage(kbase, 16384, 0, 0);
  __syncthreads();

  bf16x8 afu[2], afv[2];
  #pragma unroll
  for (int kh = 0; kh < 2; ++kh) {
    afu[kh] = *(const bf16x8*)&qu[sb * 16 + mrow][kh * 32 + kq * 8];
    afv[kh] = *(const bf16x8*)&qv[sb * 16 + mrow][kh * 32 + kq * 8];
  }

  // phase 1: content scores
  for (int c = 0; c < nc1; ++c) {
    if (c + 1 < nc1) stage(kbase, 16384, (c + 1) * 128, (c + 1) & 1);
    const bf16_t* cb = chunk[c & 1];
    #pragma unroll
    for (int t = 0; t < 2; ++t) {
      int ft = fg * 2 + t;
      int rr = ft * 16 + mrow;
      int sw = (mrow & 7) << 4;
      bf16x8 b0 = *(const bf16x8*)&cb[rr * 64 + (((kq * 16) ^ sw) >> 1)];
      bf16x8 b1 = *(const bf16x8*)&cb[rr * 64 + (((64 + kq * 16) ^ sw) >> 1)];
      f32x4 cc = {0.f, 0.f, 0.f, 0.f};
      cc = __builtin_amdgcn_mfma_f32_16x16x32_bf16(afu[0], b0, cc, 0, 0, 0);
      cc = __builtin_amdgcn_mfma_f32_16x16x32_bf16(afu[1], b1, cc, 0, 0, 0);
      #pragma unroll
      for (int r2 = 0; r2 < 4; ++r2)
        sc[(sb * 16 + kq * 4 + r2) * SC_RS + c * 128 + ft * 16 + mrow] = (bf16_t)cc[r2];
    }
    __syncthreads();
  }

  // phase 2: position scores, rel-shift scatter-add: f = j - 511 + s
  stage(rbase, 1024, c0 * 128, c0 & 1);
  __syncthreads();
  for (int c = c0; c < 8; ++c) {
    if (c < 7) stage(rbase, 1024, (c + 1) * 128, (c + 1) & 1);
    const bf16_t* cb = chunk[c & 1];
    #pragma unroll
    for (int t = 0; t < 2; ++t) {
      int ft = fg * 2 + t;
      int rr = ft * 16 + mrow;
      int sw = (mrow & 7) << 4;
      bf16x8 b0 = *(const bf16x8*)&cb[rr * 64 + (((kq * 16) ^ sw) >> 1)];
      bf16x8 b1 = *(const bf16x8*)&cb[rr * 64 + (((64 + kq * 16) ^ sw) >> 1)];
      f32x4 cc = {0.f, 0.f, 0.f, 0.f};
      cc = __builtin_amdgcn_mfma_f32_16x16x32_bf16(afv[0], b0, cc, 0, 0, 0);
      cc = __builtin_amdgcn_mfma_f32_16x16x32_bf16(afv[1], b1, cc, 0, 0, 0);
      #pragma unroll
      for (int r2 = 0; r2 < 4; ++r2) {
        int srow = sb * 16 + kq * 4 + r2;
        int f = (c * 128 + ft * 16 + mrow) - 511 + s0 + srow;
        if (f >= 0 && f < 1024) {
          float old = (float)sc[srow * SC_RS + f];
          sc[srow * SC_RS + f] = (bf16_t)(old + cc[r2]);
        }
      }
    }
    __syncthreads();
  }

  // phase 3: masked softmax
  for (int rr = 0; rr < 4; ++rr) {
    int row = w * 4 + rr;
    int fmx = s0 + row + 512;
    bf16x8 p0 = *(const bf16x8*)&sc[row * SC_RS + lane * 16];
    bf16x8 p1 = *(const bf16x8*)&sc[row * SC_RS + lane * 16 + 8];
    float vals[16];
    float mx = -1e30f;
    #pragma unroll
    for (int i = 0; i < 8; ++i) {
      vals[i] = (float)p0[i];
      vals[8 + i] = (float)p1[i];
    }
    #pragma unroll
    for (int i = 0; i < 16; ++i) {
      if (lane * 16 + i <= fmx) mx = fmaxf(mx, vals[i]);
    }
    #pragma unroll
    for (int o = 32; o; o >>= 1) mx = fmaxf(mx, __shfl_xor(mx, o));
    float sum = 0.f;
    bf16x8 e0, e1;
    #pragma unroll
    for (int i = 0; i < 16; ++i) {
      float e = (lane * 16 + i <= fmx) ? __expf(vals[i] - mx) : 0.f;
      sum += e;
      if (i < 8) e0[i] = (bf16_t)e; else e1[i - 8] = (bf16_t)e;
    }
    *(bf16x8*)&sc[row * SC_RS + lane * 16] = e0;
    *(bf16x8*)&sc[row * SC_RS + lane * 16 + 8] = e1;
    #pragma unroll
    for (int o = 32; o; o >>= 1) sum += __shfl_xor(sum, o);
    if (lane == 0) rrecip[row] = 1.f / sum;
  }
  __syncthreads();

  // phase 4: AV
  {
    int dt = fg;
    const bf16_t* vp = vT + ((size_t)(bh * 64 + dt * 16 + mrow)) * 1024;
    f32x4 acc = {0.f, 0.f, 0.f, 0.f};
    for (int kk = 0; kk < nkk; ++kk) {
      bf16x8 af = *(const bf16x8*)&sc[(sb * 16 + mrow) * SC_RS + kk * 32 + kq * 8];
      bf16x8 bv = *(const bf16x8*)(vp + kk * 32 + kq * 8);
      acc = __builtin_amdgcn_mfma_f32_16x16x32_bf16(af, bv, acc, 0, 0, 0);
    }
    #pragma unroll
    for (int r2 = 0; r2 < 4; ++r2) {
      int srow = sb * 16 + kq * 4 + r2;
      float ov = acc[r2] * rrecip[srow];
      av[((size_t)((s0 + srow) * 8 + b)) * 1024 + h * 64 + dt * 16 + mrow] = (bf16_t)ov;
    }
  }
}

// ---------------- host ----------------
extern "C" void kernel_launch(void* const* d_in, const int* in_sizes, int n_in,
                              void* d_out, int out_size, void* d_ws, size_t ws_size,
                              hipStream_t stream) {
  const float* inputs = (const float*)d_in[0];
  const float* pos_emb = (const float*)d_in[1];
  const float* memory = (const float*)d_in[2];
  const float* u = (const float*)d_in[3];
  const float* v = (const float*)d_in[4];
  const float* Wkv = (const float*)d_in[6];
  const float* bkv = (const float*)d_in[7];
  const float* Wq = (const float*)d_in[8];
  const float* bq = (const float*)d_in[9];
  const float* Wpos = (const float*)d_in[10];
  const float* bpos = (const float*)d_in[11];
  const float* Wproj = (const float*)d_in[12];
  const float* bproj = (const float*)d_in[13];
  const float* ln1_g = (const float*)d_in[14];
  const float* ln1_b = (const float*)d_in[15];
  const float* ln2_g = (const float*)d_in[16];
  const float* ln2_b = (const float*)d_in[17];
  const float* g1_bg = (const float*)d_in[24];
  const float* g2_bg = (const float*)d_in[31];
  const float* mlp_W1 = (const float*)d_in[32];
  const float* mlp_b1 = (const float*)d_in[33];
  const float* mlp_W2 = (const float*)d_in[34];
  const float* mlp_b2 = (const float*)d_in[35];

  char* ws = (char*)d_ws;
  const size_t MB = 1ull << 20;
  bf16_t* x1 = (bf16_t*)(ws + 0);
  bf16_t* kvb = (bf16_t*)(ws + 16 * MB);
  bf16_t* qb = (bf16_t*)(ws + 48 * MB);
  bf16_t* peb = (bf16_t*)(ws + 56 * MB);
  bf16_t* rposb = (bf16_t*)(ws + 58 * MB);
  bf16_t* vTb = (bf16_t*)(ws + 60 * MB);
  bf16_t* avb = (bf16_t*)(ws + 76 * MB);
  bf16_t* a1b = (bf16_t*)(ws + 84 * MB);
  bf16_t* inb = (bf16_t*)(ws + 92 * MB);
  float* rzh = (float*)(ws + 0);
  float* zbuf = (float*)(ws + 48 * MB);
  bf16_t* rxb = (bf16_t*)(ws + 64 * MB);
  float* o1f = (float*)(ws + 72 * MB);
  bf16_t* o1b = (bf16_t*)(ws + 88 * MB);
  bf16_t* x2b = (bf16_t*)(ws + 96 * MB);
  bf16_t* m1b = (bf16_t*)(ws + 104 * MB);
  bf16_t* m2b = (bf16_t*)(ws + 136 * MB);
  bf16_t* WkvT = (bf16_t*)(ws + 144 * MB);
  bf16_t* WqT = (bf16_t*)(ws + 148 * MB);
  bf16_t* WposT = (bf16_t*)(ws + 150 * MB);
  bf16_t* WprojT = (bf16_t*)(ws + 152 * MB);
  bf16_t* g1cat3 = (bf16_t*)(ws + 154 * MB);
  bf16_t* g1cat2 = (bf16_t*)(ws + 160 * MB);
  bf16_t* g1ug = (bf16_t*)(ws + 164 * MB);
  bf16_t* g2cat3 = (bf16_t*)(ws + 166 * MB);
  bf16_t* g2cat2 = (bf16_t*)(ws + 172 * MB);
  bf16_t* g2ug = (bf16_t*)(ws + 176 * MB);
  bf16_t* W1T = (bf16_t*)(ws + 178 * MB);
  bf16_t* W2T = (bf16_t*)(ws + 186 * MB);

  WtArgs wa;
  const float* srcs[18] = {Wkv, Wq, Wpos, Wproj,
                           (const float*)d_in[18], (const float*)d_in[20], (const float*)d_in[22],
                           (const float*)d_in[19], (const float*)d_in[21], (const float*)d_in[23],
                           (const float*)d_in[25], (const float*)d_in[27], (const float*)d_in[29],
                           (const float*)d_in[26], (const float*)d_in[28], (const float*)d_in[30],
                           mlp_W1, mlp_W2};
  bf16_t* dsts[18] = {WkvT, WqT, WposT, WprojT,
                      g1cat3, g1cat3 + 1024 * 1024, g1cat3 + 2 * 1024 * 1024,
                      g1cat2, g1cat2 + 1024 * 1024, g1ug,
                      g2cat3, g2cat3 + 1024 * 1024, g2cat3 + 2 * 1024 * 1024,
                      g2cat2, g2cat2 + 1024 * 1024, g2ug,
                      W1T, W2T};
  int kds[18] = {1024, 1024, 1024, 1024, 1024, 1024, 1024, 1024, 1024,
                 1024, 1024, 1024, 1024, 1024, 1024, 1024, 1024, 4096};
  int nds[18] = {2048, 1024, 1024, 1024, 1024, 1024, 1024, 1024, 1024,
                 1024, 1024, 1024, 1024, 1024, 1024, 1024, 4096, 1024};
  int cum = 0;
  for (int i = 0; i < 18; ++i) {
    wa.src[i] = srcs[i];
    wa.dst[i] = dsts[i];
    wa.kdim[i] = kds[i];
    wa.ndim[i] = nds[i];
    cum += (nds[i] >> 6) * (kds[i] >> 6);
    wa.tile_end[i] = cum;
  }
  wt_batch<<<cum, 256, 0, stream>>>(wa);

  cvt_kernel<<<4096, 256, 0, stream>>>(inputs, inb, 1048576);
  cvt_kernel<<<1024, 256, 0, stream>>>(pos_emb, peb, 262144);
  ln_kernel<<<8192, 256, 0, stream>>>(memory, inputs, 4096, ln1_g, ln1_b, x1);

  auto gemm = [&](const bf16_t* A, const bf16_t* BT, const float* bias, float* Cf, bf16_t* Cb,
                  const float* Cacc, int ldacc, const float* xin, const float* zin, int M, int N,
                  int K, int act) {
    gemm_bf16<<<dim3(N / 128, M / 128), 256, 0, stream>>>(A, BT, bias, Cf, Cb, Cacc, ldacc, xin,
                                                          zin, M, N, K, act);
  };
  auto gemm2 = [&](const bf16_t* A, const bf16_t* BT, const float* bias, float* Cf, bf16_t* Cb,
                   const float* Cacc, int ldacc, const float* xin, int M, int N, int K, int act) {
    gemm256<<<(M / 256) * (N / 256), 512, 0, stream>>>(A, BT, bias, Cf, Cb, Cacc, ldacc, xin, M,
                                                       N, K, act);
  };

  gemm2(x1, WkvT, bkv, nullptr, kvb, nullptr, 0, nullptr, 8192, 2048, 1024, 0);
  gemm(x1 + (size_t)4096 * 1024, WqT, bq, nullptr, qb, nullptr, 0, nullptr, nullptr, 4096, 1024,
       1024, 0);
  gemm(peb, WposT, bpos, nullptr, rposb, nullptr, 0, nullptr, nullptr, 1024, 1024, 1024, 0);
  vT_kernel<<<dim3(16, 128), 256, 0, stream>>>(kvb, vTb);
  attn_kernel<<<dim3(128, 16), 512, 0, stream>>>(qb, kvb, rposb, vTb, u, v, avb);
  gemm(avb, WprojT, bproj, nullptr, a1b, nullptr, 0, nullptr, nullptr, 4096, 1024, 1024, 1);

  // GRU gate 1
  gemm2(a1b, g1cat3, nullptr, rzh, nullptr, nullptr, 0, nullptr, 4096, 3072, 1024, 0);
  gemm2(inb, g1cat2, g1_bg, zbuf, rxb, rzh, 3072, inputs, 4096, 2048, 1024, 4);
  gemm(rxb, g1ug, nullptr, o1f, o1b, rzh + 2048, 3072, inputs, zbuf, 4096, 1024, 1024, 5);

  ln_kernel<<<4096, 256, 0, stream>>>(o1f, nullptr, 1 << 30, ln2_g, ln2_b, x2b);
  gemm2(x2b, W1T, mlp_b1, nullptr, m1b, nullptr, 0, nullptr, 4096, 4096, 1024, 1);
  gemm(m1b, W2T, mlp_b2, nullptr, m2b, nullptr, 0, nullptr, nullptr, 4096, 1024, 4096, 1);

  // GRU gate 2
  gemm2(m2b, g2cat3, nullptr, rzh, nullptr, nullptr, 0, nullptr, 4096, 3072, 1024, 0);
  gemm2(o1b, g2cat2, g2_bg, zbuf, rxb, rzh, 3072, o1f, 4096, 2048, 1024, 4);
  gemm(rxb, g2ug, nullptr, (float*)d_out, nullptr, rzh + 2048, 3072, o1f, zbuf, 4096, 1024, 1024,
       5);
}

// Round 5
// 886.734 us; speedup vs baseline: 1.0937x; 1.0937x over previous
//
#include <hip/hip_runtime.h>

// GTrXL fused pipeline v4.1: barrier-free pipelined attention, fused GRU gates
// (K=2048 stacked GEMM), 8-phase 256^2 GEMM for big shapes.
// v4 bug fixed: inputs cvt launch covered only 1/4 of rows (n4 262144 -> 1048576).

typedef __bf16 bf16_t;
typedef __bf16 bf16x4 __attribute__((ext_vector_type(4)));
typedef __bf16 bf16x8 __attribute__((ext_vector_type(8)));
typedef float f32x4 __attribute__((ext_vector_type(4)));

typedef __attribute__((address_space(1))) const void* GPtr;
typedef __attribute__((address_space(3))) void* LPtr;

// ---------------- fp32 -> bf16 convert with output row stride ----------------
__global__ __launch_bounds__(256) void cvt_kernel(const float* __restrict__ in,
                                                  bf16_t* __restrict__ out, int n4, int ld4) {
  int i = blockIdx.x * 256 + threadIdx.x;
  if (i >= n4) return;
  int row = i >> 8, c = i & 255;  // 1024 f32 per row
  f32x4 v = ((const f32x4*)in)[i];
  bf16x4 o;
  o[0] = (bf16_t)v[0]; o[1] = (bf16_t)v[1]; o[2] = (bf16_t)v[2]; o[3] = (bf16_t)v[3];
  *(bf16x4*)&out[(size_t)row * ld4 + c * 4] = o;
}

// ---------------- batched weight transpose: W[K][N] f32 -> WT[N][ld] bf16 ----------------
#define NWT 20
struct WtArgs {
  const float* src[NWT];
  bf16_t* dst[NWT];
  int kdim[NWT];
  int ndim[NWT];
  int ld[NWT];
  int tile_end[NWT];
};

__global__ __launch_bounds__(256) void wt_batch(WtArgs a) {
  int t = blockIdx.x;
  int i = 0;
  while (i < NWT - 1 && t >= a.tile_end[i]) ++i;
  int lt = t - (i ? a.tile_end[i - 1] : 0);
  const float* W = a.src[i];
  bf16_t* WT = a.dst[i];
  int K = a.kdim[i], N = a.ndim[i], ld = a.ld[i];
  int ntx = N >> 6;
  int n0 = (lt % ntx) * 64, k0 = (lt / ntx) * 64;
  int tid = threadIdx.x;
  int c = tid & 63, r0 = tid >> 6;
  if (W == nullptr) {  // zero-fill block
    #pragma unroll
    for (int p = 0; p < 16; ++p) {
      int r = r0 + p * 4;
      WT[(size_t)(n0 + r) * ld + k0 + c] = (bf16_t)0.f;
    }
    return;
  }
  __shared__ float tbuf[64][65];
  #pragma unroll
  for (int p = 0; p < 16; ++p) {
    int r = r0 + p * 4;
    tbuf[r][c] = W[(size_t)(k0 + r) * N + n0 + c];
  }
  __syncthreads();
  #pragma unroll
  for (int p = 0; p < 16; ++p) {
    int r = r0 + p * 4;
    WT[(size_t)(n0 + r) * ld + k0 + c] = (bf16_t)tbuf[c][r];
  }
}

// ---------------- LayerNorm over D=1024 ----------------
__global__ __launch_bounds__(256) void ln_kernel(const float* __restrict__ srcA,
                                                 const float* __restrict__ srcB, int splitRow,
                                                 const float* __restrict__ g,
                                                 const float* __restrict__ be,
                                                 bf16_t* __restrict__ out) {
  const int row = blockIdx.x, tid = threadIdx.x;
  const float* src = (srcB != nullptr && row >= splitRow)
                         ? srcB + (size_t)(row - splitRow) * 1024
                         : srcA + (size_t)row * 1024;
  f32x4 x = ((const f32x4*)src)[tid];
  __shared__ float red[8];
  float s = x[0] + x[1] + x[2] + x[3];
  #pragma unroll
  for (int o = 32; o; o >>= 1) s += __shfl_down(s, o);
  if ((tid & 63) == 0) red[tid >> 6] = s;
  __syncthreads();
  if (tid == 0) red[4] = (red[0] + red[1] + red[2] + red[3]) * (1.f / 1024.f);
  __syncthreads();
  const float mean = red[4];
  f32x4 d = x - mean;
  float s2 = d[0] * d[0] + d[1] * d[1] + d[2] * d[2] + d[3] * d[3];
  #pragma unroll
  for (int o = 32; o; o >>= 1) s2 += __shfl_down(s2, o);
  if ((tid & 63) == 0) red[tid >> 6] = s2;
  __syncthreads();
  if (tid == 0) red[5] = rsqrtf((red[0] + red[1] + red[2] + red[3]) * (1.f / 1024.f) + 1e-5f);
  __syncthreads();
  const float rstd = red[5];
  f32x4 gg = ((const f32x4*)g)[tid], bb = ((const f32x4*)be)[tid];
  bf16x4 o4;
  #pragma unroll
  for (int j = 0; j < 4; ++j) o4[j] = (bf16_t)(d[j] * rstd * gg[j] + bb[j]);
  ((bf16x4*)(out + (size_t)row * 1024))[tid] = o4;
}

// ---------------- shared epilogue ----------------
__device__ __forceinline__ void epi_store(float vv, int row, int colb, int N, int act,
                                          const float* bias, float* Cf, int ldcf, bf16_t* Cb,
                                          int ldcb, bf16_t* zio, const float* Cacc,
                                          const float* xin) {
  if (act <= 1) {
    if (bias) vv += bias[colb];
    if (act == 1) vv = fmaxf(vv, 0.f);
    if (Cf) Cf[(size_t)row * ldcf + colb] = vv;
    if (Cb) Cb[(size_t)row * ldcb + colb] = (bf16_t)vv;
  } else if (act == 4) {
    if (colb < 1024) {
      float r = 1.f / (1.f + __expf(-vv));
      Cb[(size_t)row * 1024 + colb] = (bf16_t)(r * xin[(size_t)row * 1024 + colb]);
    } else if (colb < 2048) {
      float z = 1.f / (1.f + __expf(-(vv - bias[colb - 1024])));
      zio[(size_t)row * 1024 + colb - 1024] = (bf16_t)z;
    } else {
      Cf[(size_t)row * 1024 + colb - 2048] = vv;
    }
  } else {  // act 5
    size_t e = (size_t)row * 1024 + colb;
    float hh = tanhf(vv + Cacc[e]);
    float xx = xin[e], zz = (float)zio[e];
    float o = xx + zz * (hh - xx);
    if (Cf) Cf[e] = o;
    if (Cb) Cb[(size_t)row * ldcb + colb] = (bf16_t)o;
  }
}

// ---------------- 128^2 MFMA GEMM ----------------
__global__ __launch_bounds__(256) void gemm_bf16(const bf16_t* __restrict__ A,
                                                 const bf16_t* __restrict__ BT,
                                                 const float* __restrict__ bias,
                                                 float* __restrict__ Cf, int ldcf,
                                                 bf16_t* __restrict__ Cb, int ldcb,
                                                 bf16_t* __restrict__ zio,
                                                 const float* __restrict__ Cacc,
                                                 const float* __restrict__ xin,
                                                 int M, int N, int K, int act) {
  __shared__ bf16_t As[128 * 32];
  __shared__ bf16_t Bs[128 * 32];
  const int tid = threadIdx.x, lane = tid & 63, wid = tid >> 6;
  const int nx = gridDim.x;
  int flat = blockIdx.y * nx + blockIdx.x;
  int nwg = nx * gridDim.y;
  int q8 = nwg >> 3, r8 = nwg & 7;
  int xcd = flat & 7, idx = flat >> 3;
  int wg = (xcd < r8) ? xcd * (q8 + 1) + idx : r8 * (q8 + 1) + (xcd - r8) * q8 + idx;
  const int m0 = (wg / nx) * 128, n0 = (wg % nx) * 128;
  const int wm = (wid >> 1) * 64, wn = (wid & 1) * 64;
  const int mrow = lane & 15, kq = lane >> 4;
  f32x4 acc[4][4] = {};
  for (int k0 = 0; k0 < K; k0 += 32) {
    #pragma unroll
    for (int p = 0; p < 2; ++p) {
      int cbase = p * 256 + wid * 64;
      int c = cbase + lane;
      const bf16_t* ga = A + (size_t)(m0 + (c >> 2)) * K + k0 + (c & 3) * 8;
      const bf16_t* gb = BT + (size_t)(n0 + (c >> 2)) * K + k0 + (c & 3) * 8;
      __builtin_amdgcn_global_load_lds((GPtr)ga, (LPtr)(&As[cbase * 8]), 16, 0, 0);
      __builtin_amdgcn_global_load_lds((GPtr)gb, (LPtr)(&Bs[cbase * 8]), 16, 0, 0);
    }
    __syncthreads();
    bf16x8 af[4], bfr[4];
    #pragma unroll
    for (int i = 0; i < 4; ++i) {
      af[i] = *(const bf16x8*)&As[(wm + i * 16 + mrow) * 32 + kq * 8];
      bfr[i] = *(const bf16x8*)&Bs[(wn + i * 16 + mrow) * 32 + kq * 8];
    }
    #pragma unroll
    for (int i = 0; i < 4; ++i)
      #pragma unroll
      for (int j = 0; j < 4; ++j)
        acc[i][j] = __builtin_amdgcn_mfma_f32_16x16x32_bf16(af[i], bfr[j], acc[i][j], 0, 0, 0);
    __syncthreads();
  }
  #pragma unroll
  for (int i = 0; i < 4; ++i)
    #pragma unroll
    for (int j = 0; j < 4; ++j) {
      int colb = n0 + wn + j * 16 + mrow;
      #pragma unroll
      for (int r2 = 0; r2 < 4; ++r2) {
        int row = m0 + wm + i * 16 + kq * 4 + r2;
        epi_store(acc[i][j][r2], row, colb, N, act, bias, Cf, ldcf, Cb, ldcb, zio, Cacc, xin);
      }
    }
}

// ---------------- 8-phase 256^2 GEMM ----------------
#define MFMA_QUAD(MH, NH)                                                                     \
  _Pragma("unroll") for (int ii = 0; ii < 4; ++ii)                                            \
  _Pragma("unroll") for (int jj = 0; jj < 2; ++jj)                                            \
  _Pragma("unroll") for (int ks = 0; ks < 2; ++ks)                                            \
    acc[(MH)*4 + ii][(NH)*2 + jj] = __builtin_amdgcn_mfma_f32_16x16x32_bf16(                  \
        a[ii][ks], bfr[(NH)*2 + jj][ks], acc[(MH)*4 + ii][(NH)*2 + jj], 0, 0, 0);

#define PH_SYNC()                                                                             \
  __builtin_amdgcn_s_barrier();                                                               \
  asm volatile("s_waitcnt lgkmcnt(0)" ::: "memory");                                          \
  __builtin_amdgcn_sched_barrier(0);                                                          \
  __builtin_amdgcn_s_setprio(1)

#define PH_END()                                                                              \
  __builtin_amdgcn_s_setprio(0);                                                              \
  __builtin_amdgcn_s_barrier();                                                               \
  __builtin_amdgcn_sched_barrier(0)

#define PH_END_VM()                                                                           \
  __builtin_amdgcn_s_setprio(0);                                                              \
  asm volatile("s_waitcnt vmcnt(4)" ::: "memory");                                            \
  __builtin_amdgcn_s_barrier();                                                               \
  __builtin_amdgcn_sched_barrier(0)

__global__ __launch_bounds__(512, 2) void gemm256(const bf16_t* __restrict__ A,
                                                  const bf16_t* __restrict__ BT,
                                                  const float* __restrict__ bias,
                                                  float* __restrict__ Cf, int ldcf,
                                                  bf16_t* __restrict__ Cb, int ldcb,
                                                  bf16_t* __restrict__ zio,
                                                  const float* __restrict__ xin,
                                                  int M, int N, int K, int act) {
  __shared__ bf16_t lds[65536];
  const int tid = threadIdx.x, lane = tid & 63, w = tid >> 6;
  const int mrow = lane & 15, kq = lane >> 4;
  const int nx = N >> 8;
  int nwg = gridDim.x;
  int flat = blockIdx.x;
  int q8 = nwg >> 3, r8 = nwg & 7;
  int xcd = flat & 7, idxb = flat >> 3;
  int wg = (xcd < r8) ? xcd * (q8 + 1) + idxb : r8 * (q8 + 1) + (xcd - r8) * q8 + idxb;
  const int m0 = (wg / nx) * 256, n0 = (wg % nx) * 256;

  const bf16_t* pA = A + (size_t)m0 * K;
  const bf16_t* pB = BT + (size_t)n0 * K;

  auto stage = [&](const bf16_t* base, int kt, int hh, int buf, int area) {
    #pragma unroll
    for (int li = 0; li < 2; ++li) {
      int row = li * 64 + w * 8 + (lane >> 3);
      const bf16_t* src =
          base + (size_t)(hh * 128 + row) * K + kt * 64 + (((lane & 7) ^ (lane >> 3)) << 3);
      __builtin_amdgcn_global_load_lds(
          (GPtr)src, (LPtr)&lds[buf * 32768 + area * 16384 + hh * 8192 + li * 4096 + w * 512],
          16, 0, 0);
    }
  };
  auto ldA = [&](int buf, int i, int ks) -> bf16x8 {
    int row = i * 16 + mrow;
    int off = (row << 6) + ((ks * 32 + kq * 8) ^ ((row & 7) << 3));
    return *(const bf16x8*)&lds[buf * 32768 + (w >> 2) * 8192 + off];
  };
  auto ldB = [&](int buf, int j, int ks) -> bf16x8 {
    int row = (w & 1) * 64 + j * 16 + mrow;
    int off = (row << 6) + ((ks * 32 + kq * 8) ^ ((row & 7) << 3));
    return *(const bf16x8*)&lds[buf * 32768 + 16384 + ((w & 3) >> 1) * 8192 + off];
  };

  f32x4 acc[8][4] = {};
  bf16x8 a[4][2], bfr[4][2];

  const int KT = K >> 6;
  stage(pA, 0, 0, 0, 0);
  stage(pA, 0, 1, 0, 0);
  stage(pB, 0, 0, 0, 1);
  stage(pB, 0, 1, 0, 1);
  stage(pB, 1, 0, 1, 1);
  stage(pB, 1, 1, 1, 1);
  asm volatile("s_waitcnt vmcnt(4)" ::: "memory");
  __builtin_amdgcn_s_barrier();
  __builtin_amdgcn_sched_barrier(0);

  for (int it = 0; it < KT / 2; ++it) {
    int kt = 2 * it;
    int ktA1 = min(kt + 1, KT - 1);
    int kt2 = min(kt + 2, KT - 1);
    int kt3 = min(kt + 3, KT - 1);
    #pragma unroll
    for (int ii = 0; ii < 4; ++ii) { a[ii][0] = ldA(0, ii, 0); a[ii][1] = ldA(0, ii, 1); }
    #pragma unroll
    for (int jj = 0; jj < 2; ++jj) { bfr[jj][0] = ldB(0, jj, 0); bfr[jj][1] = ldB(0, jj, 1); }
    stage(pA, ktA1, 0, 1, 0);
    PH_SYNC(); MFMA_QUAD(0, 0); PH_END();
    #pragma unroll
    for (int jj = 0; jj < 2; ++jj) { bfr[2 + jj][0] = ldB(0, 2 + jj, 0); bfr[2 + jj][1] = ldB(0, 2 + jj, 1); }
    stage(pA, ktA1, 1, 1, 0);
    PH_SYNC(); MFMA_QUAD(0, 1); PH_END();
    #pragma unroll
    for (int ii = 0; ii < 4; ++ii) { a[ii][0] = ldA(0, 4 + ii, 0); a[ii][1] = ldA(0, 4 + ii, 1); }
    stage(pB, kt2, 0, 0, 1);
    PH_SYNC(); MFMA_QUAD(1, 0); PH_END();
    stage(pB, kt2, 1, 0, 1);
    PH_SYNC(); MFMA_QUAD(1, 1); PH_END_VM();
    #pragma unroll
    for (int ii = 0; ii < 4; ++ii) { a[ii][0] = ldA(1, ii, 0); a[ii][1] = ldA(1, ii, 1); }
    #pragma unroll
    for (int jj = 0; jj < 2; ++jj) { bfr[jj][0] = ldB(1, jj, 0); bfr[jj][1] = ldB(1, jj, 1); }
    stage(pA, kt2, 0, 0, 0);
    PH_SYNC(); MFMA_QUAD(0, 0); PH_END();
    #pragma unroll
    for (int jj = 0; jj < 2; ++jj) { bfr[2 + jj][0] = ldB(1, 2 + jj, 0); bfr[2 + jj][1] = ldB(1, 2 + jj, 1); }
    stage(pA, kt2, 1, 0, 0);
    PH_SYNC(); MFMA_QUAD(0, 1); PH_END();
    #pragma unroll
    for (int ii = 0; ii < 4; ++ii) { a[ii][0] = ldA(1, 4 + ii, 0); a[ii][1] = ldA(1, 4 + ii, 1); }
    stage(pB, kt3, 0, 1, 1);
    PH_SYNC(); MFMA_QUAD(1, 0); PH_END();
    stage(pB, kt3, 1, 1, 1);
    PH_SYNC(); MFMA_QUAD(1, 1); PH_END_VM();
  }

  #pragma unroll
  for (int i = 0; i < 8; ++i)
    #pragma unroll
    for (int j = 0; j < 4; ++j) {
      int colb = n0 + (w & 3) * 64 + j * 16 + mrow;
      #pragma unroll
      for (int r2 = 0; r2 < 4; ++r2) {
        int row = m0 + (w >> 2) * 128 + i * 16 + kq * 4 + r2;
        epi_store(acc[i][j][r2], row, colb, N, act, bias, Cf, ldcf, Cb, ldcb, zio, nullptr, xin);
      }
    }
}

// ---------------- value transpose ----------------
__global__ __launch_bounds__(256) void vT_kernel(const bf16_t* __restrict__ kv,
                                                 bf16_t* __restrict__ vT) {
  int ft = blockIdx.x;
  int bh = blockIdx.y;
  int b = bh >> 4, h = bh & 15;
  __shared__ bf16_t t[64][68];
  int tid = threadIdx.x;
  {
    int dq = (tid & 15) * 4, fr = tid >> 4;
    #pragma unroll
    for (int p = 0; p < 4; ++p) {
      int fi = fr + p * 16;
      const bf16_t* src = kv + ((size_t)((ft * 64 + fi) * 8 + b)) * 2048 + 1024 + h * 64 + dq;
      *(bf16x4*)&t[fi][dq] = *(const bf16x4*)src;
    }
  }
  __syncthreads();
  {
    int fl = tid & 63, dr = tid >> 6;
    #pragma unroll
    for (int p = 0; p < 16; ++p) {
      int d = dr + p * 4;
      vT[((size_t)(bh * 64 + d)) * 1024 + ft * 64 + fl] = t[fl][d];
    }
  }
}

// ---------------- attention v4: barrier-free pipelined QK, shift-at-write rel-pos ---------
__global__ __launch_bounds__(512) void attn_kernel(const bf16_t* __restrict__ q,
                                                   const bf16_t* __restrict__ kv,
                                                   const bf16_t* __restrict__ rpos,
                                                   const bf16_t* __restrict__ vT,
                                                   const float* __restrict__ u,
                                                   const float* __restrict__ v,
                                                   bf16_t* __restrict__ av) {
  const int bh = blockIdx.x, st = blockIdx.y;
  const int b = bh >> 4, h = bh & 15;
  const int s0 = st * 16;
  const int tid = threadIdx.x, lane = tid & 63, w = tid >> 6;
  const int mrow = lane & 15, kq = lane >> 4;

  __shared__ bf16_t sc1[16 * 1032];          // content scores -> P
  __shared__ bf16_t sc2[16 * 1032];          // position scores (pre-shifted to f)
  __shared__ bf16_t slots[8 * 4 * 1024];     // per-wave 4-slot ring of 16x64 tiles
  __shared__ bf16_t qu[16][72], qv[16][72];
  __shared__ float part[16][68];
  __shared__ float rrecip[16];

  if (tid < 256) {
    int sl = tid >> 4, dq = (tid & 15) * 4;
    const bf16_t* qp = q + ((size_t)((s0 + sl) * 8 + b)) * 1024 + h * 64 + dq;
    bf16x4 q4 = *(const bf16x4*)qp;
    f32x4 uu = *(const f32x4*)(u + h * 64 + dq);
    f32x4 vv = *(const f32x4*)(v + h * 64 + dq);
    #pragma unroll
    for (int j = 0; j < 4; ++j) {
      float qf = (float)q4[j];
      qu[sl][dq + j] = (bf16_t)((qf + uu[j]) * 0.125f);
      qv[sl][dq + j] = (bf16_t)((qf + vv[j]) * 0.125f);
    }
  }
  __syncthreads();

  bf16x8 afu[2], afv[2];
  afu[0] = *(const bf16x8*)&qu[mrow][kq * 8];
  afu[1] = *(const bf16x8*)&qu[mrow][32 + kq * 8];
  afv[0] = *(const bf16x8*)&qv[mrow][kq * 8];
  afv[1] = *(const bf16x8*)&qv[mrow][32 + kq * 8];

  const int nf1 = (s0 + 543) >> 4;                       // content f-tiles
  const int jt0 = (s0 >= 496) ? 0 : ((496 - s0) >> 4);   // first rpos j-tile
  const int ncw = (nf1 > w) ? (nf1 - w + 7) / 8 : 0;
  const int npw = (64 - jt0 > w) ? (64 - jt0 - w + 7) / 8 : 0;
  const int ntot = ncw + npw;
  const bf16_t* kbase = kv + (size_t)b * 2048 + h * 64;  // row stride 16384
  const bf16_t* rbase = rpos + h * 64;                   // row stride 1024
  const int swzsrc = (((lane & 7) ^ (lane >> 3)) << 4) >> 1;

  auto issue = [&](int i) {
    int slot = i & 3;
    const bf16_t* base;
    size_t rstr;
    int r0;
    if (i < ncw) { base = kbase; rstr = 16384; r0 = (w + 8 * i) * 16; }
    else { base = rbase; rstr = 1024; r0 = (jt0 + w + 8 * (i - ncw)) * 16; }
    #pragma unroll
    for (int li = 0; li < 2; ++li) {
      const bf16_t* src = base + (size_t)(r0 + li * 8 + (lane >> 3)) * rstr + swzsrc;
      __builtin_amdgcn_global_load_lds((GPtr)src, (LPtr)&slots[(w * 4 + slot) * 1024 + li * 512],
                                       16, 0, 0);
    }
  };
  auto compute = [&](int i) {
    int slot = i & 3;
    const bf16_t* sb = &slots[(w * 4 + slot) * 1024];
    int swz = (mrow & 7) << 4;
    bf16x8 b0 = *(const bf16x8*)&sb[(mrow * 128 + ((kq * 16) ^ swz)) >> 1];
    bf16x8 b1 = *(const bf16x8*)&sb[(mrow * 128 + ((64 + kq * 16) ^ swz)) >> 1];
    f32x4 cc = {0.f, 0.f, 0.f, 0.f};
    if (i < ncw) {
      cc = __builtin_amdgcn_mfma_f32_16x16x32_bf16(afu[0], b0, cc, 0, 0, 0);
      cc = __builtin_amdgcn_mfma_f32_16x16x32_bf16(afu[1], b1, cc, 0, 0, 0);
      int fb = (w + 8 * i) * 16 + mrow;
      #pragma unroll
      for (int r2 = 0; r2 < 4; ++r2) sc1[(kq * 4 + r2) * 1032 + fb] = (bf16_t)cc[r2];
    } else {
      cc = __builtin_amdgcn_mfma_f32_16x16x32_bf16(afv[0], b0, cc, 0, 0, 0);
      cc = __builtin_amdgcn_mfma_f32_16x16x32_bf16(afv[1], b1, cc, 0, 0, 0);
      int jb = (jt0 + w + 8 * (i - ncw)) * 16 + mrow - 511 + s0;
      #pragma unroll
      for (int r2 = 0; r2 < 4; ++r2) {
        int srow = kq * 4 + r2;
        int f = jb + srow;
        if (f >= 0) sc2[srow * 1032 + f] = (bf16_t)cc[r2];
      }
    }
  };

  for (int i = 0; i < ntot && i < 3; ++i) issue(i);
  for (int i = 0; i < ntot; ++i) {
    int rem = ntot - 1 - i;
    if (rem >= 2) asm volatile("s_waitcnt vmcnt(4)" ::: "memory");
    else if (rem == 1) asm volatile("s_waitcnt vmcnt(2)" ::: "memory");
    else asm volatile("s_waitcnt vmcnt(0)" ::: "memory");
    __builtin_amdgcn_sched_barrier(0);
    compute(i);
    if (i + 3 < ntot) issue(i + 3);
  }
  __syncthreads();

  // softmax: wave w owns rows 2w, 2w+1. lo half (f<512) never masked.
  #pragma unroll
  for (int rr = 0; rr < 2; ++rr) {
    int row = w * 2 + rr;
    int fmx = s0 + row;  // hi-half unmasked iff lane*8+i <= fmx
    bf16x8 c0 = *(const bf16x8*)&sc1[row * 1032 + lane * 8];
    bf16x8 c1 = *(const bf16x8*)&sc1[row * 1032 + 512 + lane * 8];
    bf16x8 p0 = *(const bf16x8*)&sc2[row * 1032 + lane * 8];
    bf16x8 p1 = *(const bf16x8*)&sc2[row * 1032 + 512 + lane * 8];
    float lo[8], hi[8];
    float mx = -1e30f;
    #pragma unroll
    for (int i = 0; i < 8; ++i) {
      lo[i] = (float)c0[i] + (float)p0[i];
      mx = fmaxf(mx, lo[i]);
    }
    #pragma unroll
    for (int i = 0; i < 8; ++i) {
      hi[i] = (float)c1[i] + (float)p1[i];
      if (lane * 8 + i <= fmx) mx = fmaxf(mx, hi[i]);
    }
    #pragma unroll
    for (int o = 32; o; o >>= 1) mx = fmaxf(mx, __shfl_xor(mx, o));
    float sum = 0.f;
    bf16x8 e0, e1;
    #pragma unroll
    for (int i = 0; i < 8; ++i) {
      float e = __expf(lo[i] - mx);
      sum += e;
      e0[i] = (bf16_t)e;
    }
    #pragma unroll
    for (int i = 0; i < 8; ++i) {
      float e = (lane * 8 + i <= fmx) ? __expf(hi[i] - mx) : 0.f;
      sum += e;
      e1[i] = (bf16_t)e;
    }
    *(bf16x8*)&sc1[row * 1032 + lane * 8] = e0;
    *(bf16x8*)&sc1[row * 1032 + 512 + lane * 8] = e1;
    #pragma unroll
    for (int o = 32; o; o >>= 1) sum += __shfl_xor(sum, o);
    if (lane == 0) rrecip[row] = 1.f / sum;
  }
  __syncthreads();

  // AV: wave = (dt = w&3, half = w>>2); halves combine via LDS
  {
    int nkk = (s0 + 559) >> 5;
    int nk2 = (nkk + 1) >> 1;
    int dt = w & 3, hf = w >> 2;
    int ks = hf ? nk2 : 0, ke = hf ? nkk : nk2;
    const bf16_t* vp = vT + ((size_t)(bh * 64 + dt * 16 + mrow)) * 1024;
    f32x4 acc = {0.f, 0.f, 0.f, 0.f};
    for (int kk = ks; kk < ke; ++kk) {
      bf16x8 af = *(const bf16x8*)&sc1[mrow * 1032 + kk * 32 + kq * 8];
      bf16x8 bv = *(const bf16x8*)(vp + kk * 32 + kq * 8);
      acc = __builtin_amdgcn_mfma_f32_16x16x32_bf16(af, bv, acc, 0, 0, 0);
    }
    if (hf) {
      #pragma unroll
      for (int r2 = 0; r2 < 4; ++r2) part[kq * 4 + r2][dt * 16 + mrow] = acc[r2];
    }
    __syncthreads();
    if (!hf) {
      #pragma unroll
      for (int r2 = 0; r2 < 4; ++r2) {
        int srow = kq * 4 + r2;
        float ov = (acc[r2] + part[srow][dt * 16 + mrow]) * rrecip[srow];
        av[((size_t)((s0 + srow) * 8 + b)) * 1024 + h * 64 + dt * 16 + mrow] = (bf16_t)ov;
      }
    }
  }
}

// ---------------- host ----------------
extern "C" void kernel_launch(void* const* d_in, const int* in_sizes, int n_in,
                              void* d_out, int out_size, void* d_ws, size_t ws_size,
                              hipStream_t stream) {
  const float* inputs = (const float*)d_in[0];
  const float* pos_emb = (const float*)d_in[1];
  const float* memory = (const float*)d_in[2];
  const float* u = (const float*)d_in[3];
  const float* v = (const float*)d_in[4];
  const float* Wkv = (const float*)d_in[6];
  const float* bkv = (const float*)d_in[7];
  const float* Wq = (const float*)d_in[8];
  const float* bq = (const float*)d_in[9];
  const float* Wpos = (const float*)d_in[10];
  const float* bpos = (const float*)d_in[11];
  const float* Wproj = (const float*)d_in[12];
  const float* bproj = (const float*)d_in[13];
  const float* ln1_g = (const float*)d_in[14];
  const float* ln1_b = (const float*)d_in[15];
  const float* ln2_g = (const float*)d_in[16];
  const float* ln2_b = (const float*)d_in[17];
  const float* g1_bg = (const float*)d_in[24];
  const float* g2_bg = (const float*)d_in[31];
  const float* mlp_W1 = (const float*)d_in[32];
  const float* mlp_b1 = (const float*)d_in[33];
  const float* mlp_W2 = (const float*)d_in[34];
  const float* mlp_b2 = (const float*)d_in[35];

  char* ws = (char*)d_ws;
  const size_t MB = 1ull << 20;
  bf16_t* x1 = (bf16_t*)(ws + 0);          // 16MB, dead after kv/q gemms
  bf16_t* kvb = (bf16_t*)(ws + 16 * MB);   // 32MB, dead after attn
  bf16_t* qb = (bf16_t*)(ws + 48 * MB);    // 8MB, dead after attn
  bf16_t* peb = (bf16_t*)(ws + 56 * MB);   // 2MB
  bf16_t* rposb = (bf16_t*)(ws + 58 * MB); // 2MB
  bf16_t* vTb = (bf16_t*)(ws + 60 * MB);   // 16MB, dead after attn
  bf16_t* avb = (bf16_t*)(ws + 76 * MB);   // 8MB, dead after proj
  bf16_t* yx1 = (bf16_t*)(ws + 84 * MB);   // 16MB [y=a1 | x=inputs], dead after gate1-G1
  bf16_t* rxb = (bf16_t*)(ws + 0);         // 8MB (over x1)
  bf16_t* zb = (bf16_t*)(ws + 8 * MB);     // 8MB (over x1)
  float* hpart = (float*)(ws + 16 * MB);   // 16MB (over kvb)
  float* o1f = (float*)(ws + 32 * MB);     // 16MB (over kvb)
  bf16_t* x2b = (bf16_t*)(ws + 48 * MB);   // 8MB (over qb)
  bf16_t* m1b = (bf16_t*)(ws + 60 * MB);   // 32MB (over vTb/avb/yx1-head)
  bf16_t* yx2 = (bf16_t*)(ws + 92 * MB);   // 16MB [y=m2 | x=o1]
  bf16_t* WkvT = (bf16_t*)(ws + 108 * MB);
  bf16_t* WqT = (bf16_t*)(ws + 112 * MB);
  bf16_t* WposT = (bf16_t*)(ws + 114 * MB);
  bf16_t* WprojT = (bf16_t*)(ws + 116 * MB);
  bf16_t* W1T = (bf16_t*)(ws + 118 * MB);
  bf16_t* W2T = (bf16_t*)(ws + 126 * MB);
  bf16_t* g1WU = (bf16_t*)(ws + 134 * MB);  // 3072x2048
  bf16_t* g1UgT = (bf16_t*)(ws + 146 * MB);
  bf16_t* g2WU = (bf16_t*)(ws + 148 * MB);
  bf16_t* g2UgT = (bf16_t*)(ws + 160 * MB);  // ends 162MB

  WtArgs wa;
  {
    const float* srcs[NWT] = {Wkv, Wq, Wpos, Wproj, mlp_W1, mlp_W2,
                              (const float*)d_in[18], (const float*)d_in[19],
                              (const float*)d_in[20], (const float*)d_in[21],
                              (const float*)d_in[22], nullptr,
                              (const float*)d_in[25], (const float*)d_in[26],
                              (const float*)d_in[27], (const float*)d_in[28],
                              (const float*)d_in[29], nullptr,
                              (const float*)d_in[23], (const float*)d_in[30]};
    bf16_t* dsts[NWT] = {WkvT, WqT, WposT, WprojT, W1T, W2T,
                         g1WU, g1WU + 1024, g1WU + 1024 * 2048, g1WU + 1024 * 2048 + 1024,
                         g1WU + 2048 * 2048, g1WU + 2048 * 2048 + 1024,
                         g2WU, g2WU + 1024, g2WU + 1024 * 2048, g2WU + 1024 * 2048 + 1024,
                         g2WU + 2048 * 2048, g2WU + 2048 * 2048 + 1024,
                         g1UgT, g2UgT};
    int kds[NWT] = {1024, 1024, 1024, 1024, 1024, 4096, 1024, 1024, 1024, 1024,
                    1024, 1024, 1024, 1024, 1024, 1024, 1024, 1024, 1024, 1024};
    int nds[NWT] = {2048, 1024, 1024, 1024, 4096, 1024, 1024, 1024, 1024, 1024,
                    1024, 1024, 1024, 1024, 1024, 1024, 1024, 1024, 1024, 1024};
    int lds_[NWT] = {1024, 1024, 1024, 1024, 1024, 4096, 2048, 2048, 2048, 2048,
                     2048, 2048, 2048, 2048, 2048, 2048, 2048, 2048, 1024, 1024};
    int cum = 0;
    for (int i = 0; i < NWT; ++i) {
      wa.src[i] = srcs[i];
      wa.dst[i] = dsts[i];
      wa.kdim[i] = kds[i];
      wa.ndim[i] = nds[i];
      wa.ld[i] = lds_[i];
      cum += (nds[i] >> 6) * (kds[i] >> 6);
      wa.tile_end[i] = cum;
    }
    wt_batch<<<cum, 256, 0, stream>>>(wa);
  }

  // FIX: inputs is 4096 rows x 1024 f32 = 1048576 f32x4 (v4 passed 262144/1024 blocks)
  cvt_kernel<<<4096, 256, 0, stream>>>(inputs, yx1 + 1024, 1048576, 2048);  // x-half of [y|x]
  cvt_kernel<<<1024, 256, 0, stream>>>(pos_emb, peb, 262144, 1024);
  ln_kernel<<<8192, 256, 0, stream>>>(memory, inputs, 4096, ln1_g, ln1_b, x1);

  auto g128 = [&](const bf16_t* A, const bf16_t* BT, const float* bias, float* Cf, int ldcf,
                  bf16_t* Cb, int ldcb, bf16_t* zio, const float* Cacc, const float* xin, int M,
                  int N, int K, int act) {
    gemm_bf16<<<dim3(N / 128, M / 128), 256, 0, stream>>>(A, BT, bias, Cf, ldcf, Cb, ldcb, zio,
                                                          Cacc, xin, M, N, K, act);
  };
  auto g256 = [&](const bf16_t* A, const bf16_t* BT, const float* bias, float* Cf, int ldcf,
                  bf16_t* Cb, int ldcb, bf16_t* zio, const float* xin, int M, int N, int K,
                  int act) {
    gemm256<<<(M / 256) * (N / 256), 512, 0, stream>>>(A, BT, bias, Cf, ldcf, Cb, ldcb, zio, xin,
                                                       M, N, K, act);
  };

  g256(x1, WkvT, bkv, nullptr, 0, kvb, 2048, nullptr, nullptr, 8192, 2048, 1024, 0);
  g128(x1 + (size_t)4096 * 1024, WqT, bq, nullptr, 0, qb, 1024, nullptr, nullptr, nullptr, 4096,
       1024, 1024, 0);
  g128(peb, WposT, bpos, nullptr, 0, rposb, 1024, nullptr, nullptr, nullptr, 1024, 1024, 1024, 0);
  vT_kernel<<<dim3(16, 128), 256, 0, stream>>>(kvb, vTb);
  attn_kernel<<<dim3(128, 32), 512, 0, stream>>>(qb, kvb, rposb, vTb, u, v, avb);
  g128(avb, WprojT, bproj, nullptr, 0, yx1, 2048, nullptr, nullptr, nullptr, 4096, 1024, 1024, 1);

  // GRU gate 1: single fused pass1 (K=2048) + combine
  g256(yx1, g1WU, g1_bg, hpart, 1024, rxb, 1024, zb, inputs, 4096, 3072, 2048, 4);
  g128(rxb, g1UgT, nullptr, o1f, 1024, yx2 + 1024, 2048, zb, hpart, inputs, 4096, 1024, 1024, 5);

  ln_kernel<<<4096, 256, 0, stream>>>(o1f, nullptr, 1 << 30, ln2_g, ln2_b, x2b);
  g256(x2b, W1T, mlp_b1, nullptr, 0, m1b, 4096, nullptr, nullptr, 4096, 4096, 1024, 1);
  g128(m1b, W2T, mlp_b2, nullptr, 0, yx2, 2048, nullptr, nullptr, nullptr, 4096, 1024, 4096, 1);

  // GRU gate 2
  g256(yx2, g2WU, g2_bg, hpart, 1024, rxb, 1024, zb, o1f, 4096, 3072, 2048, 4);
  g128(rxb, g2UgT, nullptr, (float*)d_out, 1024, nullptr, 0, zb, hpart, o1f, 4096, 1024, 1024, 5);
}